// Round 10
// baseline (240.078 us; speedup 1.0000x reference)
//
#include <hip/hip_runtime.h>
#include <hip/hip_bf16.h>

#define BB 2
#define NN 8192
#define SPL 16
#define CAND (NN/SPL)
#define NPTS (BB*NN)

// ---- workspace layout (units: 4-byte words), high-water ~17.9 MB ----
#define PART_OFF 0u                     /* [256][NPTS] = 4,194,304 w; dead after k2 */
#define IDX_OFF  4194304u               /* 262,144 w */
#define WT_OFF   4456448u               /* 4 mats x 4096 bf16 = 8,192 w */
#define QB_OFF   0u                     /* overlays PART (born in k34, after k2) */
#define KVB_OFF  1048576u               /* packed bf16 kv, overlays PART */

typedef __attribute__((ext_vector_type(8))) short bf16x8;
typedef __attribute__((ext_vector_type(4))) float f32x4;

__device__ __forceinline__ unsigned umn(unsigned a, unsigned b) {
#if __has_builtin(__builtin_elementwise_min)
  return __builtin_elementwise_min(a, b);
#else
  return a < b ? a : b;
#endif
}
__device__ __forceinline__ unsigned umx(unsigned a, unsigned b) {
#if __has_builtin(__builtin_elementwise_max)
  return __builtin_elementwise_max(a, b);
#else
  return a < b ? b : a;
#endif
}

__device__ inline unsigned short f2bf(float x) {
  __hip_bfloat16 b = __float2bfloat16(x);
  return *(unsigned short*)&b;
}

// column-block rotate swizzle for conflict-free ds_read_b128 fragments
#define HCOL(c, j) ((((((c) >> 3) + (j)) & 7) << 3) | ((c) & 7))

// ============================ K1: KNN, batch-8 OEMS selection =================
// key = (19 high dist bits | 13-bit idx). Per 8 candidates: OEMS-8 sort DESC
// (19 CE), lower-16 of merge(m asc16, b desc8) = 8 mins + 32-CE bitonic clean.
// Live set m16+b8 = 24 regs -> no AGPR banking (R9's hidden 2x overhead).
// Distances from RAW pos (wave-uniform scalar loads), no pos4 staging.
__global__ __launch_bounds__(256) void k1_knn(const float* __restrict__ pos,
                                              unsigned* __restrict__ part)
{
  const int tid = threadIdx.x;
  const int g = blockIdx.x * 256 + tid;
  const int s = blockIdx.y;
  const int bu = __builtin_amdgcn_readfirstlane(g >> 13);
  const float qx = pos[g * 3 + 0], qy = pos[g * 3 + 1], qz = pos[g * 3 + 2];
  const float* __restrict__ cp = pos + (bu * NN + s * CAND) * 3;  // uniform
  const unsigned jb = (unsigned)(s * CAND);
  unsigned m[16];
#pragma unroll
  for (int i = 0; i < 16; i++) m[i] = 0xFFFFFFFFu;

  // Batcher odd-even mergesort network for n=8 (19 comparators)
  constexpr int OE8[19][2] = {
    {0,1},{2,3},{4,5},{6,7},
    {0,2},{1,3},{4,6},{5,7},
    {1,2},{5,6},
    {0,4},{1,5},{2,6},{3,7},
    {2,4},{3,5},
    {1,2},{3,4},{5,6}
  };

  for (int j0 = 0; j0 < CAND; j0 += 8) {
    float c[24];
#pragma unroll
    for (int i = 0; i < 24; i++) c[i] = cp[j0 * 3 + i];   // scalar loads
    unsigned b[8];
#pragma unroll
    for (int i = 0; i < 8; i++) {
      float dx = c[i * 3 + 0] - qx;
      float dy = c[i * 3 + 1] - qy;
      float dz = c[i * 3 + 2] - qz;
      float d2 = fmaf(dx, dx, fmaf(dy, dy, dz * dz));
      b[i] = (__float_as_uint(d2) & 0xFFFFE000u) | (jb + (unsigned)(j0 + i));
    }
    // sort b DESC (low index gets max)
#pragma unroll
    for (int cc = 0; cc < 19; cc++) {
      const int x = OE8[cc][0], y = OE8[cc][1];
      unsigned lo = umn(b[x], b[y]);
      unsigned hi = umx(b[x], b[y]);
      b[x] = hi; b[y] = lo;
    }
    // lower-16 of merge(m asc16, [inf x8, b desc8]) then 4-stage clean -> asc
#pragma unroll
    for (int i = 0; i < 8; i++) m[8 + i] = umn(m[8 + i], b[i]);
#pragma unroll
    for (int d = 8; d; d >>= 1) {
#pragma unroll
      for (int i = 0; i < 16; i++) {
        if ((i & d) == 0) {
          const int l = i | d;
          unsigned lo = umn(m[i], m[l]);
          unsigned hi = umx(m[i], m[l]);
          m[i] = lo; m[l] = hi;
        }
      }
    }
  }
#pragma unroll
  for (int i = 0; i < 16; i++)
    part[(unsigned)(s * 16 + i) * NPTS + (unsigned)g] = m[i];
}

// ============================ K2: merge 16 lists; +wt bf16-T staging blocks ===
__global__ __launch_bounds__(256) void k2_merge(
    const unsigned* __restrict__ part, int* __restrict__ knn_idx,
    const float* __restrict__ pe_w2, const float* __restrict__ at_w1,
    const float* __restrict__ at_w2, const float* __restrict__ out_w,
    unsigned short* __restrict__ wt)
{
  if (blockIdx.x >= 64) {   // staging: wt[m*4096 + f*64 + c] = W_m[c*64+f]
    const int t = (blockIdx.x - 64) * 256 + threadIdx.x;
    const float* s;
    switch (t >> 12) {
      case 0: s = pe_w2; break;
      case 1: s = at_w1; break;
      case 2: s = at_w2; break;
      default: s = out_w; break;
    }
    const int idx = t & 4095, f = idx >> 6, c = idx & 63;
    wt[t] = f2bf(s[c * 64 + f]);
    return;
  }
  const int g = blockIdx.x * 256 + threadIdx.x;
  unsigned run[16];
#pragma unroll
  for (int i = 0; i < 16; i++) run[i] = part[i * NPTS + g];
#pragma unroll
  for (int l = 1; l < SPL; l++) {
#pragma unroll
    for (int i = 0; i < 16; i++)
      run[i] = umn(run[i], part[(l * 16 + 15 - i) * NPTS + g]);
#pragma unroll
    for (int d = 8; d; d >>= 1) {
#pragma unroll
      for (int i = 0; i < 16; i++) {
        if ((i & d) == 0) {
          const int l2 = i | d;
          unsigned lo = umn(run[i], run[l2]);
          unsigned hi = umx(run[i], run[l2]);
          run[i] = lo; run[l2] = hi;
        }
      }
    }
  }
  const int base = (g >> 13) * NN;
  int outv[16];
#pragma unroll
  for (int i = 0; i < 16; i++) outv[i] = base + (int)(run[i] & 0x1FFFu);
  int4* o = (int4*)(knn_idx + g * 16);
  o[0] = make_int4(outv[0], outv[1], outv[2], outv[3]);
  o[1] = make_int4(outv[4], outv[5], outv[6], outv[7]);
  o[2] = make_int4(outv[8], outv[9], outv[10], outv[11]);
  o[3] = make_int4(outv[12], outv[13], outv[14], outv[15]);
}

// ============================ K34: fused emb+qkv (direct weights) =============
__global__ __launch_bounds__(256) void k34_embqkv(
    const float* __restrict__ feat,
    const float* __restrict__ emb_w, const float* __restrict__ emb_b,
    const float* __restrict__ wq, const float* __restrict__ wk,
    const float* __restrict__ wv,
    float* __restrict__ qo, unsigned* __restrict__ kvp)
{
  __shared__ float wl[16384];   // emb | q | k | v  (64 KB)
  __shared__ float xl[2048];    // 32 rows x 64     (8 KB)
  for (int i = threadIdx.x; i < 4096; i += 256) {
    wl[i] = emb_w[i];
    wl[4096 + i] = wq[i];
    wl[8192 + i] = wk[i];
    wl[12288 + i] = wv[i];
  }
  const int col = threadIdx.x & 63;
  const int rg = threadIdx.x >> 6;
  const int row0 = blockIdx.x * 32 + rg * 8;
  const int rowu = __builtin_amdgcn_readfirstlane(row0);
  __syncthreads();
  {
    float acc[8];
    float bias = emb_b[col];
#pragma unroll
    for (int r = 0; r < 8; r++) acc[r] = bias;
    for (int c = 0; c < 64; c++) {
      float w = wl[c * 64 + col];
      const float* fp = feat + rowu * 64 + c;   // uniform -> scalar loads
#pragma unroll
      for (int r = 0; r < 8; r++) acc[r] = fmaf(fp[r * 64], w, acc[r]);
    }
#pragma unroll
    for (int r = 0; r < 8; r++) xl[(rg * 8 + r) * 64 + col] = acc[r];
  }
  __syncthreads();
  float aq[8], ak[8], av[8];
#pragma unroll
  for (int r = 0; r < 8; r++) { aq[r] = 0.f; ak[r] = 0.f; av[r] = 0.f; }
  for (int c = 0; c < 64; c++) {
    float w0 = wl[4096 + c * 64 + col];
    float w1 = wl[8192 + c * 64 + col];
    float w2 = wl[12288 + c * 64 + col];
#pragma unroll
    for (int r = 0; r < 8; r++) {
      float xv = xl[(rg * 8 + r) * 64 + c];
      aq[r] = fmaf(xv, w0, aq[r]);
      ak[r] = fmaf(xv, w1, ak[r]);
      av[r] = fmaf(xv, w2, av[r]);
    }
  }
#pragma unroll
  for (int r = 0; r < 8; r++) {
    qo[(row0 + r) * 64 + col] = aq[r];
    kvp[(row0 + r) * 64 + col] =
        ((unsigned)f2bf(av[r]) << 16) | (unsigned)f2bf(ak[r]);
  }
}

// ============================ K5: MFMA fused posenc/attn/softmax/out ==========
// R9 structure (Bf in regs, launch_bounds(256,2), early kv/q gathers, packed
// bf16 kv, no softmax max-sub); raw pos + direct bias pointers (k0 removed).
__device__ inline void mv(const unsigned short* hm, const bf16x8 B[4][2],
                          const float bias[4], int ln, int s0, int s1,
                          f32x4 acc[4])
{
  bf16x8 a0 = *(const bf16x8*)(hm + ln * 64 + s0);
  bf16x8 a1 = *(const bf16x8*)(hm + ln * 64 + s1);
#pragma unroll
  for (int t = 0; t < 4; t++) {
    f32x4 a = {bias[t], bias[t], bias[t], bias[t]};
    a = __builtin_amdgcn_mfma_f32_16x16x32_bf16(a0, B[t][0], a, 0, 0, 0);
    a = __builtin_amdgcn_mfma_f32_16x16x32_bf16(a1, B[t][1], a, 0, 0, 0);
    acc[t] = a;
  }
}

__global__ __launch_bounds__(256, 2) void k5_attn(
    const float* __restrict__ pos, const float* __restrict__ qg,
    const unsigned* __restrict__ kvp, const float* __restrict__ featf,
    const float* __restrict__ pe_w1, const float* __restrict__ pe_b1,
    const float* __restrict__ pe_b2, const float* __restrict__ at_b1,
    const float* __restrict__ at_b2, const float* __restrict__ out_b,
    const unsigned short* __restrict__ wt, const int* __restrict__ knn,
    float* __restrict__ out)
{
  __shared__ unsigned short hma[4][1024];   // per-wave 16x64 bf16 h (8 KB)
  __shared__ unsigned short resm[1024];     // 16 points x 64 bf16   (2 KB)
  const int tid = threadIdx.x;
  const int wid = tid >> 6, lane = tid & 63;
  const int ln = lane & 15, quad = lane >> 4;
  unsigned short* hm = hma[wid];
  const int s0 = ((quad + ln) & 7) << 3;        // fragment swizzle offsets
  const int s1 = ((4 + quad + ln) & 7) << 3;

  bf16x8 Bf[3][4][2];                       // pe_w2^T | at_w1^T | at_w2^T frags
#pragma unroll
  for (int m = 0; m < 3; m++)
#pragma unroll
    for (int t = 0; t < 4; t++)
#pragma unroll
      for (int ks = 0; ks < 2; ks++)
        Bf[m][t][ks] = *(const bf16x8*)(wt + m * 4096 + (t * 16 + ln) * 64 +
                                        ks * 32 + quad * 8);
  bf16x8 bo[2];                             // epilogue frags (N-tile = wid)
#pragma unroll
  for (int ks = 0; ks < 2; ks++)
    bo[ks] = *(const bf16x8*)(wt + 3 * 4096 + (wid * 16 + ln) * 64 +
                              ks * 32 + quad * 8);

  float pw10 = pe_w1[lane], pw11 = pe_w1[64 + lane], pw12 = pe_w1[128 + lane];
  float pb1 = pe_b1[lane];
  float bpe[4], ba1[4], ba2[4];
#pragma unroll
  for (int t = 0; t < 4; t++) {
    bpe[t] = pe_b2[t * 16 + ln];
    ba1[t] = at_b1[t * 16 + ln];
    ba2[t] = at_b2[t * 16 + ln];
  }

  const int p0 = blockIdx.x * 16 + wid * 4;
  const int ps0 = __builtin_amdgcn_readfirstlane(p0);
  int4 cur[4];
  {
    const int4* ip4 = (const int4*)(knn + ps0 * 16);
#pragma unroll
    for (int u = 0; u < 4; u++) cur[u] = ip4[u];
  }

  for (int pp = 0; pp < 4; pp++) {
    const int p = p0 + pp;
    const int ps = __builtin_amdgcn_readfirstlane(p);
    int jj[16];
#pragma unroll
    for (int u = 0; u < 4; u++) {
      jj[u*4+0] = cur[u].x; jj[u*4+1] = cur[u].y;
      jj[u*4+2] = cur[u].z; jj[u*4+3] = cur[u].w;
    }
    // prefetch next point's indices (in flight through this whole point)
    int4 nxt[4];
    {
      const int pn = (pp < 3) ? (ps + 1) : ps;
      const int4* np4 = (const int4*)(knn + pn * 16);
#pragma unroll
      for (int u = 0; u < 4; u++) nxt[u] = np4[u];
    }
    // issue kv + q gathers EARLY: consumed only after mv1
    unsigned kvw[4][4];
#pragma unroll
    for (int r = 0; r < 4; r++) {
      const unsigned* kp = kvp + jj[quad * 4 + r] * 64 + ln;
#pragma unroll
      for (int t = 0; t < 4; t++) kvw[r][t] = kp[t * 16];
    }
    float qv[4];
#pragma unroll
    for (int t = 0; t < 4; t++) qv[t] = qg[p * 64 + t * 16 + ln];

    // posenc hidden: h1 = relu(gpos @ pe_w1 + pe_b1)
    const float* mp = pos + ps * 3;
    float pnx = mp[0], pny = mp[1], pnz = mp[2];
#pragma unroll
    for (int j = 0; j < 16; j++) {
      const float* np_ = pos + jj[j] * 3;
      float h1 = fmaf(np_[2] - pnz, pw12,
                 fmaf(np_[1] - pny, pw11,
                 fmaf(np_[0] - pnx, pw10, pb1)));
      hm[j * 64 + HCOL(lane, j)] = f2bf(fmaxf(h1, 0.f));
    }
    f32x4 accp[4];
    mv(hm, Bf[0], bpe, ln, s0, s1, accp);          // posenc (kv loads in flight)
    // hh = q - k + pe ; vpe = v + pe   (k,v unpacked from bf16 pair)
    float vpe[4][4];
#pragma unroll
    for (int r = 0; r < 4; r++) {
      const int j = quad * 4 + r;
#pragma unroll
      for (int t = 0; t < 4; t++) {
        const unsigned w = kvw[r][t];
        float kf = __uint_as_float(w << 16);
        float vf = __uint_as_float(w & 0xFFFF0000u);
        float pe = accp[t][r];
        vpe[t][r] = vf + pe;
        hm[j * 64 + HCOL(t * 16 + ln, j)] = f2bf(qv[t] - kf + pe);
      }
    }
    f32x4 acch[4];
    mv(hm, Bf[1], ba1, ln, s0, s1, acch);          // hh @ at_w1 + b
#pragma unroll
    for (int t = 0; t < 4; t++)
#pragma unroll
      for (int r = 0; r < 4; r++) {
        const int j = quad * 4 + r;
        hm[j * 64 + HCOL(t * 16 + ln, j)] = f2bf(fmaxf(acch[t][r], 0.f));
      }
    f32x4 lg[4];
    mv(hm, Bf[2], ba2, ln, s0, s1, lg);            // logits
    // per-channel softmax over 16 neighbors; logits tiny -> no max-sub needed
    const int pb = wid * 4 + pp;
#pragma unroll
    for (int t = 0; t < 4; t++) {
      float e0 = __expf(lg[t][0] * 0.125f);
      float e1 = __expf(lg[t][1] * 0.125f);
      float e2 = __expf(lg[t][2] * 0.125f);
      float e3 = __expf(lg[t][3] * 0.125f);
      float ss = (e0 + e1) + (e2 + e3);
      float dt = fmaf(e3, vpe[t][3], fmaf(e2, vpe[t][2],
                 fmaf(e1, vpe[t][1], e0 * vpe[t][0])));
      ss += __shfl_xor(ss, 16); ss += __shfl_xor(ss, 32);
      dt += __shfl_xor(dt, 16); dt += __shfl_xor(dt, 32);
      float res = dt / ss;
      if (quad == 0) resm[pb * 64 + HCOL(t * 16 + ln, pb)] = f2bf(res);
    }
#pragma unroll
    for (int u = 0; u < 4; u++) cur[u] = nxt[u];
  }
  __syncthreads();
  // epilogue: 16 points = 1 M-tile x 4 N-tiles; wave wid handles N-tile wid
  {
    const int nt = wid;
    float ob = out_b[nt * 16 + ln];
    f32x4 acc = {ob, ob, ob, ob};
#pragma unroll
    for (int ks = 0; ks < 2; ks++) {
      bf16x8 a = *(const bf16x8*)(resm + ln * 64 +
                                  (((ks * 4 + quad + ln) & 7) << 3));
      acc = __builtin_amdgcn_mfma_f32_16x16x32_bf16(a, bo[ks], acc, 0, 0, 0);
    }
#pragma unroll
    for (int r = 0; r < 4; r++) {
      const int pt = blockIdx.x * 16 + quad * 4 + r;
      const int f = nt * 16 + ln;
      out[pt * 64 + f] = acc[r] + featf[pt * 64 + f];
    }
  }
}

// ============================ launcher ========================================
extern "C" void kernel_launch(void* const* d_in, const int* in_sizes, int n_in,
                              void* d_out, int out_size, void* d_ws, size_t ws_size,
                              hipStream_t stream)
{
  (void)in_sizes; (void)n_in; (void)out_size; (void)ws_size;
  const float* pos   = (const float*)d_in[0];
  const float* feat  = (const float*)d_in[1];
  const float* emb_w = (const float*)d_in[2];
  const float* emb_b = (const float*)d_in[3];
  const float* wq    = (const float*)d_in[4];
  const float* wk    = (const float*)d_in[5];
  const float* wv    = (const float*)d_in[6];
  const float* pe_w1 = (const float*)d_in[7];
  const float* pe_b1 = (const float*)d_in[8];
  const float* pe_w2 = (const float*)d_in[9];
  const float* pe_b2 = (const float*)d_in[10];
  const float* at_w1 = (const float*)d_in[11];
  const float* at_b1 = (const float*)d_in[12];
  const float* at_w2 = (const float*)d_in[13];
  const float* at_b2 = (const float*)d_in[14];
  const float* out_w = (const float*)d_in[15];
  const float* out_b = (const float*)d_in[16];
  float* ws = (float*)d_ws;

  dim3 g1(NPTS / 256, SPL);
  k1_knn<<<g1, 256, 0, stream>>>(pos, (unsigned*)ws + PART_OFF);
  k2_merge<<<128, 256, 0, stream>>>((unsigned*)ws + PART_OFF,
      (int*)ws + IDX_OFF, pe_w2, at_w1, at_w2, out_w,
      (unsigned short*)(ws + WT_OFF));
  k34_embqkv<<<NPTS / 32, 256, 0, stream>>>(feat, emb_w, emb_b, wq, wk, wv,
      ws + QB_OFF, (unsigned*)ws + KVB_OFF);
  k5_attn<<<NPTS / 16, 256, 0, stream>>>(pos, ws + QB_OFF,
      (unsigned*)ws + KVB_OFF, feat, pe_w1, pe_b1, pe_b2, at_b1, at_b2, out_b,
      (unsigned short*)(ws + WT_OFF), (int*)ws + IDX_OFF, (float*)d_out);
}